// Round 13
// baseline (557.944 us; speedup 1.0000x reference)
//
#include <hip/hip_runtime.h>

#define B_ 512
#define T_ 512
#define F_ 128
#define H_ 32
#define C_ 6
#define CH 16            // timesteps per chunk
#define NCH (T_ / CH)    // 32 chunks

// ---------------------------------------------------------------------------
// Fused LSTM, barrier-scheduled pipeline, v3.
// 512 blocks x 320 threads (5 waves); block owns ONE batch row.
//   wave 0: scan consumer (round-8 verified math)
//   waves 1-4: producers, split by f-QUARTER (wave q owns f in [q*32,+32),
//     cols {lane, lane+64}): Wc = 64 VGPR, x-window 32 VGPR -> ~110 live,
//     under the allocator's 128 cap (rounds 10/11: >128 never granted).
// KEY CHANGE vs round 12: producers read x DIRECTLY FROM GLOBAL with
// wave-uniform addresses (L1-resident 8 KB chunk; broadcast loads on the
// otherwise-idle VMEM/scalar pipe). Round 12 staged x in LDS and re-read it
// as uniform ds_read_b128 broadcasts: ~2048 reads x 12 cyc x 2 blk/CU = 25K
// cyc of LDS pipe per phase -> phases were LDS-gated (535 us), consumer
// z-reads queued behind producer x-reads. Now LDS carries only zpart/mpart.
// Producers write f-partials zpart[q]; consumer sums 4 partials per gate
// value. Mask via per-quarter sum|x| partials (exact: no cancellation).
// Schedule (one __syncthreads per phase, depth-2 slots, verified round 10):
//   phase ph: producers compute chunk ph -> zpart[*][ph&1];
//             consumer scans chunk ph-1 <- zpart[*][(ph-1)&1].
// LDS = 72 KB -> 2 blocks/CU, all 512 blocks resident.
// ---------------------------------------------------------------------------

__device__ __forceinline__ float sigmf(float xx) {
  return __builtin_amdgcn_rcpf(1.f + __expf(-xx));
}
__device__ __forceinline__ float tanhf_(float xx) {
  return __builtin_amdgcn_rcpf(1.f + __expf(-2.f * xx)) * 2.f - 1.f;
}

__global__ __launch_bounds__(320) void k_fused(
    const float* __restrict__ x, const float* __restrict__ Wx,
    const float* __restrict__ bias, const float* __restrict__ Wh,
    const float* __restrict__ Wfc, const float* __restrict__ bfc,
    float* __restrict__ out)
{
  __shared__ float zpart[4][2][CH * 128];   // 64 KB [fq][slot][t*128+col]
  __shared__ float mpart[4][NCH][CH];       // 8 KB  [fq][chunk][t] (no reuse)

  const int tid  = threadIdx.x;
  const int wid  = tid >> 6;
  const int lane = tid & 63;
  const int row  = blockIdx.x;

  if (wid >= 1) {
    // ------------------------------ producer ------------------------------
    const int q  = wid - 1;          // f-quarter 0..3
    const int fb = q * 32;

    float Wc0[32], Wc1[32];          // cols lane / lane+64, f in [fb, fb+32)
#pragma unroll
    for (int f = 0; f < 32; ++f) {
      Wc0[f] = Wx[(size_t)(fb + f) * 128 + lane];
      Wc1[f] = Wx[(size_t)(fb + f) * 128 + 64 + lane];
    }
    const float bb0 = (q == 0) ? bias[lane] : 0.f;
    const float bb1 = (q == 0) ? bias[64 + lane] : 0.f;
    const float* xr = x + (size_t)row * (T_ * F_) + fb;

    for (int ph = 0; ph <= NCH; ++ph) {
      __syncthreads();
      if (ph >= NCH) continue;
      const int slot = ph & 1;

      for (int t = 0; t < CH; ++t) {
        // wave-uniform global loads (L1 broadcast; no LDS traffic)
        const float* xp = xr + (size_t)(ph * CH + t) * F_;
        float4 xq[8];
#pragma unroll
        for (int k = 0; k < 8; ++k) xq[k] = *(const float4*)(xp + k * 4);

        float z00 = bb0, z01 = 0.f, z10 = bb1, z11 = 0.f;
#pragma unroll
        for (int k = 0; k < 8; ++k) {
          z00 += xq[k].x * Wc0[4 * k + 0];  z01 += xq[k].y * Wc0[4 * k + 1];
          z00 += xq[k].z * Wc0[4 * k + 2];  z01 += xq[k].w * Wc0[4 * k + 3];
          z10 += xq[k].x * Wc1[4 * k + 0];  z11 += xq[k].y * Wc1[4 * k + 1];
          z10 += xq[k].z * Wc1[4 * k + 2];  z11 += xq[k].w * Wc1[4 * k + 3];
        }
        zpart[q][slot][t * 128 + lane]      = z00 + z01;   // stride-1: no conflicts
        zpart[q][slot][t * 128 + 64 + lane] = z10 + z11;

        // mask partial: sum |x| over this f-quarter (exact zero test)
        float s0 = 0.f, s1 = 0.f, s2 = 0.f, s3 = 0.f;
#pragma unroll
        for (int k = 0; k < 8; ++k) {
          s0 += fabsf(xq[k].x);  s1 += fabsf(xq[k].y);
          s2 += fabsf(xq[k].z);  s3 += fabsf(xq[k].w);
        }
        if (lane == 0) mpart[q][ph][t] = (s0 + s1) + (s2 + s3);
      }
    }
    return;
  }

  // ------------------------------ consumer ------------------------------
  const int half = lane >> 5;
  const int j    = lane & 31;
  const int colA = half * 32 + j;        // i (half0) / f (half1)
  const int colB = 64 + half * 32 + j;   // g (half0) / o (half1)

  float WhA[32], WhB[32];
#pragma unroll
  for (int f = 0; f < 32; ++f) {
    WhA[f] = Wh[f * 128 + colA];
    WhB[f] = Wh[f * 128 + colB];
  }

  float hsc[32];                         // wave-uniform (SGPR via readlane)
#pragma unroll
  for (int f = 0; f < 32; ++f) hsc[f] = 0.f;
  float cj = 0.f, hj = 0.f;

  for (int ph = 0; ph <= NCH; ++ph) {
    __syncthreads();
    if (ph < 1) continue;                // phase 0: producers fill chunk 0
    const int c    = ph - 1;
    const int slot = c & 1;

    auto zrd = [&](int s, int col) {
      return (zpart[0][slot][s * 128 + col] + zpart[1][slot][s * 128 + col])
           + (zpart[2][slot][s * 128 + col] + zpart[3][slot][s * 128 + col]);
    };
    auto mrd = [&](int s) {
      const float mv = (mpart[0][c][s] + mpart[1][c][s])
                     + (mpart[2][c][s] + mpart[3][c][s]);
      return (mv != 0.f) ? 1.f : 0.f;
    };

    // depth-4 register prefetch ring over the 16-step chunk
    float za[4], zc[4], mm[4];
#pragma unroll
    for (int u = 0; u < 4; ++u) {
      za[u] = zrd(u, colA);
      zc[u] = zrd(u, colB);
      mm[u] = mrd(u);
    }
    for (int s0 = 0; s0 < 4; ++s0) {
#pragma unroll
      for (int u = 0; u < 4; ++u) {
        const int s = s0 * 4 + u;
        float zA0 = za[u], zA1 = 0.f;
        float zB0 = zc[u], zB1 = 0.f;
        const float m = mm[u];
        if (s0 < 3) {                    // refill slot u with step s+4
          za[u] = zrd(s + 4, colA);
          zc[u] = zrd(s + 4, colB);
          mm[u] = mrd(s + 4);
        }
        // recurrent matvec: 64 v_fmac (sgpr*vgpr), 4 independent chains
#pragma unroll
        for (int f = 0; f < 16; ++f) {
          zA0 += hsc[2 * f]     * WhA[2 * f];
          zA1 += hsc[2 * f + 1] * WhA[2 * f + 1];
          zB0 += hsc[2 * f]     * WhB[2 * f];
          zB1 += hsc[2 * f + 1] * WhB[2 * f + 1];
        }
        const float zA = zA0 + zA1;           // half0: zi, half1: zf
        const float zB = zB0 + zB1;           // half0: zg, half1: zo
        const float oA = __shfl_xor(zA, 32);
        const float oB = __shfl_xor(zB, 32);
        const float zi = half ? oA : zA;
        const float zf = half ? zA : oA;
        const float zg = half ? oB : zB;
        const float zo = half ? zB : oB;

        const float ig = sigmf(zi);
        const float fg = sigmf(zf);
        const float gg = tanhf_(zg);
        const float og = sigmf(zo);
        const float cn = fg * cj + ig * gg;
        const float hn = og * tanhf_(cn);
        cj += m * (cn - cj);          // masked: keep previous state if m==0
        hj += m * (hn - hj);

        // broadcast h: 32 independent v_readlane -> uniform scalars
#pragma unroll
        for (int f = 0; f < 32; ++f)
          hsc[f] = __uint_as_float(__builtin_amdgcn_readlane(__float_as_uint(hj), f));
      }
    }
  }

  // FC + softmax (all lanes redundant from uniform h; lane 0 writes)
  float logits[C_];
#pragma unroll
  for (int c = 0; c < C_; ++c) {
    float aa = bfc[c];
#pragma unroll
    for (int f = 0; f < 32; ++f) aa += hsc[f] * Wfc[f * C_ + c];
    logits[c] = aa;
  }
  if (lane == 0) {
    float mx = logits[0];
#pragma unroll
    for (int c = 1; c < C_; ++c) mx = fmaxf(mx, logits[c]);
    float e[C_], sden = 0.f;
#pragma unroll
    for (int c = 0; c < C_; ++c) { e[c] = __expf(logits[c] - mx); sden += e[c]; }
    const float rs = 1.f / sden;
#pragma unroll
    for (int c = 0; c < C_; ++c) out[(size_t)row * C_ + c] = e[c] * rs;
  }
}

// ---------------------------------------------------------------------------
extern "C" void kernel_launch(void* const* d_in, const int* in_sizes, int n_in,
                              void* d_out, int out_size, void* d_ws, size_t ws_size,
                              hipStream_t stream) {
  const float* x   = (const float*)d_in[0];
  const float* Wx  = (const float*)d_in[1];
  const float* Wh  = (const float*)d_in[2];
  const float* bv  = (const float*)d_in[3];
  const float* Wfc = (const float*)d_in[4];
  const float* bfc = (const float*)d_in[5];
  float* out = (float*)d_out;

  k_fused<<<B_, 320, 0, stream>>>(x, Wx, bv, Wh, Wfc, bfc, out);
}

// Round 14
// 318.439 us; speedup vs baseline: 1.7521x; 1.7521x over previous
//
#include <hip/hip_runtime.h>

#define B_ 512
#define T_ 512
#define F_ 128
#define H_ 32
#define C_ 6
#define CH 32            // timesteps per LDS chunk in k_lstm
#define NCH (T_ / CH)    // 16 chunks

// ---------------------------------------------------------------------------
// Kernel 1: xz[row][c] = x[row,:] @ Wx[:,c] + bias[c],  row = b*T+t
// Plain [b][t][128] layout. mask[row] = any(x[row,:] != 0).  (verified, ~105us)
// ---------------------------------------------------------------------------
__global__ __launch_bounds__(256, 2) void k_xz(
    const float* __restrict__ x, const float* __restrict__ W,
    const float* __restrict__ bias, float* __restrict__ xz,
    float* __restrict__ mask)
{
  __shared__ float xl[128 * 64];   // 32 KB, XOR-swizzled rows
  __shared__ float wl[64 * 128];   // 32 KB, plain
  const int tid = threadIdx.x;
  const int m0  = blockIdx.x * 128;
  const int cg  = tid & 15;
  const int rg  = tid >> 4;

  float4 xpre[8], wpre[8];
  int rowbits = 0;

  auto load_chunk = [&](int ch) {
#pragma unroll
    for (int k = 0; k < 8; ++k) {
      const int u = tid + k * 256, r = u >> 4, q = u & 15;
      xpre[k] = *(const float4*)(x + (size_t)(m0 + r) * 128 + ch * 64 + q * 4);
    }
#pragma unroll
    for (int k = 0; k < 8; ++k) {
      const int u = tid + k * 256, f = u >> 5, q = u & 31;
      wpre[k] = *(const float4*)(W + (size_t)(ch * 64 + f) * 128 + q * 4);
    }
  };
  auto mask_chunk = [&]() {
#pragma unroll
    for (int k = 0; k < 8; ++k) {
      const float4 v = xpre[k];
      int nb = ((v.x != 0.f) || (v.y != 0.f) || (v.z != 0.f) || (v.w != 0.f)) ? 1 : 0;
      nb |= __shfl_xor(nb, 1); nb |= __shfl_xor(nb, 2);
      nb |= __shfl_xor(nb, 4); nb |= __shfl_xor(nb, 8);
      rowbits |= nb << k;
    }
  };
  auto write_chunk = [&]() {
#pragma unroll
    for (int k = 0; k < 8; ++k) {
      const int u = tid + k * 256, r = u >> 4, q = u & 15;
      *(float4*)(xl + r * 64 + ((q * 4) ^ (((r >> 3) & 3) << 2))) = xpre[k];
    }
#pragma unroll
    for (int k = 0; k < 8; ++k) {
      const int u = tid + k * 256, f = u >> 5, q = u & 31;
      *(float4*)(wl + f * 128 + q * 4) = wpre[k];
    }
  };

  float acc[8][8];
#pragma unroll
  for (int r = 0; r < 8; ++r)
#pragma unroll
    for (int u = 0; u < 8; ++u) acc[r][u] = 0.f;

  auto compute = [&]() {
#pragma unroll 2
    for (int fq = 0; fq < 16; ++fq) {
      float4 xv[8];
#pragma unroll
      for (int r = 0; r < 8; ++r)
        xv[r] = *(const float4*)(xl + (rg * 8 + r) * 64 + ((fq * 4) ^ ((rg & 3) << 2)));
#pragma unroll
      for (int ff = 0; ff < 4; ++ff) {
        const float* wr = wl + (fq * 4 + ff) * 128 + cg * 4;
        const float4 wa = *(const float4*)(wr);
        const float4 wb = *(const float4*)(wr + 64);
#pragma unroll
        for (int r = 0; r < 8; ++r) {
          const float xs = (ff == 0) ? xv[r].x : (ff == 1) ? xv[r].y
                         : (ff == 2) ? xv[r].z : xv[r].w;
          acc[r][0] += xs * wa.x;  acc[r][1] += xs * wa.y;
          acc[r][2] += xs * wa.z;  acc[r][3] += xs * wa.w;
          acc[r][4] += xs * wb.x;  acc[r][5] += xs * wb.y;
          acc[r][6] += xs * wb.z;  acc[r][7] += xs * wb.w;
        }
      }
    }
  };

  load_chunk(0);
  mask_chunk();
  write_chunk();
  __syncthreads();
  load_chunk(1);
  compute();
  __syncthreads();
  mask_chunk();
  write_chunk();
  __syncthreads();
  compute();

  float bb[8];
#pragma unroll
  for (int u = 0; u < 4; ++u) {
    bb[u]     = bias[cg * 4 + u];
    bb[4 + u] = bias[64 + cg * 4 + u];
  }
#pragma unroll
  for (int r = 0; r < 8; ++r) {
    float* op = xz + (size_t)(m0 + rg * 8 + r) * 128;
    float4 o0 = { acc[r][0] + bb[0], acc[r][1] + bb[1], acc[r][2] + bb[2], acc[r][3] + bb[3] };
    float4 o1 = { acc[r][4] + bb[4], acc[r][5] + bb[5], acc[r][6] + bb[6], acc[r][7] + bb[7] };
    *(float4*)(op + cg * 4)      = o0;
    *(float4*)(op + 64 + cg * 4) = o1;
  }
  if ((tid & 15) == 0) {
#pragma unroll
    for (int k = 0; k < 8; ++k)
      mask[m0 + k * 16 + rg] = (rowbits >> k) & 1 ? 1.f : 0.f;
  }
}

// ---------------------------------------------------------------------------
// Kernel 2: LSTM scan + FC + softmax.  512 blocks x 64 threads, 1 row/wave.
// Round-8 verified lane scheme (2 gate cols/lane, shfl_xor(32) exchange,
// readlane h-broadcast).  NEW: xz is staged into LDS chunk-by-chunk with
// the issue-early/write-late pattern -- global loads for chunk k+1 are
// issued in 4 groups during chunk k's scan, each group ds_written 4 steps
// (~1000 cyc) after issue, so the compiler's vmcnt(0) before the ds_write
// never stalls.  Per-step gate reads are ds_read_b32 from LDS (2-way bank
// aliasing = free), pipelined by a depth-4 register ring under compiler
// lgkmcnt.  This removes the ~450-cyc L3 load latency that sat on the
// serial path in every global-load variant (rounds 2-8: 650-770 cyc/step).
// Mask row (2 KB) staged once at start.
// ---------------------------------------------------------------------------
__device__ __forceinline__ float sigmf(float xx) {
  return __builtin_amdgcn_rcpf(1.f + __expf(-xx));
}
__device__ __forceinline__ float tanhf_(float xx) {
  return __builtin_amdgcn_rcpf(1.f + __expf(-2.f * xx)) * 2.f - 1.f;
}

__global__ __launch_bounds__(64) void k_lstm(
    const float* __restrict__ xz, const float* __restrict__ mask,
    const float* __restrict__ Wh, const float* __restrict__ Wfc,
    const float* __restrict__ bfc, float* __restrict__ out)
{
  __shared__ float xch[2][CH][128];   // 32 KB double-buffered z chunks
  __shared__ float mld[T_];           // 2 KB mask row

  const int lane = threadIdx.x;
  const int half = lane >> 5;
  const int j    = lane & 31;
  const int b    = blockIdx.x;
  const int colA = half * 32 + j;        // i (half0) / f (half1)
  const int colB = 64 + half * 32 + j;   // g (half0) / o (half1)

  const float* xrow = xz + (size_t)b * (T_ * 128);
  const float* mrow = mask + (size_t)b * T_;

  // one-time: stage mask row (8 coalesced loads -> LDS)
  {
    float mv[8];
#pragma unroll
    for (int c = 0; c < 8; ++c) mv[c] = mrow[c * 64 + lane];
#pragma unroll
    for (int c = 0; c < 8; ++c) mld[c * 64 + lane] = mv[c];
  }

  float WhA[32], WhB[32];
#pragma unroll
  for (int f = 0; f < 32; ++f) {
    WhA[f] = Wh[f * 128 + colA];
    WhB[f] = Wh[f * 128 + colB];
  }

  // prologue: stage chunk 0 into slot 0 (16 calls, 4 groups of 4)
  {
    float4 xl[4];
#pragma unroll
    for (int g = 0; g < 4; ++g) {
#pragma unroll
      for (int u = 0; u < 4; ++u)
        xl[u] = *(const float4*)(xrow + (g * 4 + u) * 256 + lane * 4);
#pragma unroll
      for (int u = 0; u < 4; ++u)
        *(float4*)(&xch[0][0][0] + (g * 4 + u) * 256 + lane * 4) = xl[u];
    }
  }

  float hsc[32];                         // wave-uniform (SGPR via readlane)
#pragma unroll
  for (int f = 0; f < 32; ++f) hsc[f] = 0.f;
  float cj = 0.f, hj = 0.f;

  float4 stg[4];                         // in-flight staging regs (16 VGPR)

  for (int k = 0; k < NCH; ++k) {
    const int slot = k & 1;
    const float* zb = &xch[slot][0][0];
    float* zn = &xch[slot ^ 1][0][0];
    const float* mb = &mld[k * CH];
    const float* xnext = xrow + (size_t)(k + 1) * (CH * 128);
    const bool more = (k + 1 < NCH);

    // ring preload: steps 0..3 of this chunk (once per 32 steps)
    float za[4], zc[4], mm[4];
#pragma unroll
    for (int u = 0; u < 4; ++u) {
      za[u] = zb[u * 128 + colA];
      zc[u] = zb[u * 128 + colB];
      mm[u] = mb[u];
    }

    for (int s0 = 0; s0 < 8; ++s0) {
      // T14 staging: even s0 -> issue group (s0>>1); odd s0 -> ds_write it
      if (more) {
        const int g = s0 >> 1;
        if ((s0 & 1) == 0) {
#pragma unroll
          for (int u = 0; u < 4; ++u)
            stg[u] = *(const float4*)(xnext + (g * 4 + u) * 256 + lane * 4);
        } else {
#pragma unroll
          for (int u = 0; u < 4; ++u)
            *(float4*)(zn + (g * 4 + u) * 256 + lane * 4) = stg[u];
        }
      }

#pragma unroll
      for (int u = 0; u < 4; ++u) {
        const int s = s0 * 4 + u;
        const float m = mm[u];
        float a0 = za[u], a1 = 0.f, a2 = 0.f, a3 = 0.f;
        float b0 = zc[u], b1 = 0.f, b2 = 0.f, b3 = 0.f;
        if (s0 < 7) {                    // refill ring slot u with step s+4
          za[u] = zb[(s + 4) * 128 + colA];
          zc[u] = zb[(s + 4) * 128 + colB];
          mm[u] = mb[s + 4];
        }
        // recurrent matvec: 64 v_fmac (sgpr*vgpr), 8 independent chains
#pragma unroll
        for (int f = 0; f < 8; ++f) {
          a0 += hsc[4 * f + 0] * WhA[4 * f + 0];
          a1 += hsc[4 * f + 1] * WhA[4 * f + 1];
          a2 += hsc[4 * f + 2] * WhA[4 * f + 2];
          a3 += hsc[4 * f + 3] * WhA[4 * f + 3];
          b0 += hsc[4 * f + 0] * WhB[4 * f + 0];
          b1 += hsc[4 * f + 1] * WhB[4 * f + 1];
          b2 += hsc[4 * f + 2] * WhB[4 * f + 2];
          b3 += hsc[4 * f + 3] * WhB[4 * f + 3];
        }
        const float zA = (a0 + a1) + (a2 + a3);   // half0: zi, half1: zf
        const float zB = (b0 + b1) + (b2 + b3);   // half0: zg, half1: zo
        const float oA = __shfl_xor(zA, 32);
        const float oB = __shfl_xor(zB, 32);
        const float zi = half ? oA : zA;
        const float zf = half ? zA : oA;
        const float zg = half ? oB : zB;
        const float zo = half ? zB : oB;

        const float ig = sigmf(zi);
        const float fg = sigmf(zf);
        const float gg = tanhf_(zg);
        const float og = sigmf(zo);
        const float cn = fg * cj + ig * gg;
        const float hn = og * tanhf_(cn);
        cj += m * (cn - cj);          // masked: keep previous state if m==0
        hj += m * (hn - hj);

        // broadcast h: 32 independent v_readlane -> uniform scalars
#pragma unroll
        for (int f = 0; f < 32; ++f)
          hsc[f] = __uint_as_float(__builtin_amdgcn_readlane(__float_as_uint(hj), f));
      }
    }
  }

  // FC + softmax (all lanes redundant from uniform h; lane 0 writes)
  float logits[C_];
#pragma unroll
  for (int c = 0; c < C_; ++c) {
    float aa = bfc[c];
#pragma unroll
    for (int f = 0; f < 32; ++f) aa += hsc[f] * Wfc[f * C_ + c];
    logits[c] = aa;
  }
  if (lane == 0) {
    float mx = logits[0];
#pragma unroll
    for (int c = 1; c < C_; ++c) mx = fmaxf(mx, logits[c]);
    float e[C_], sden = 0.f;
#pragma unroll
    for (int c = 0; c < C_; ++c) { e[c] = __expf(logits[c] - mx); sden += e[c]; }
    const float rs = 1.f / sden;
#pragma unroll
    for (int c = 0; c < C_; ++c) out[(size_t)b * C_ + c] = e[c] * rs;
  }
}

// ---------------------------------------------------------------------------
extern "C" void kernel_launch(void* const* d_in, const int* in_sizes, int n_in,
                              void* d_out, int out_size, void* d_ws, size_t ws_size,
                              hipStream_t stream) {
  const float* x   = (const float*)d_in[0];
  const float* Wx  = (const float*)d_in[1];
  const float* Wh  = (const float*)d_in[2];
  const float* bv  = (const float*)d_in[3];
  const float* Wfc = (const float*)d_in[4];
  const float* bfc = (const float*)d_in[5];
  float* out = (float*)d_out;

  float* xz   = (float*)d_ws;                                       // [B][T][128] = 128 MB
  float* mask = (float*)((char*)d_ws + (size_t)B_ * T_ * 128 * 4);  // [B][T] = 1 MB

  k_xz<<<(B_ * T_) / 128, 256, 0, stream>>>(x, Wx, bv, xz, mask);
  k_lstm<<<B_, 64, 0, stream>>>(xz, mask, Wh, Wfc, bfc, out);
}

// Round 15
// 283.893 us; speedup vs baseline: 1.9653x; 1.1217x over previous
//
#include <hip/hip_runtime.h>

#define B_ 512
#define T_ 512
#define F_ 128
#define H_ 32
#define C_ 6
#define CH 8             // timesteps per DMA chunk in k_lstm
#define NCH (T_ / CH)    // 64 chunks

typedef float f32x2 __attribute__((ext_vector_type(2)));
#define AS3(p) ((__attribute__((address_space(3))) void*)(p))
#define AS1(p) ((const __attribute__((address_space(1))) void*)(p))

// ---------------------------------------------------------------------------
// Kernel 1: xz[row][c] = x[row,:] @ Wx[:,c] + bias[c],  row = b*T+t
// Plain [b][t][128] layout. mask[row] = any(x[row,:] != 0).  (verified ~105us)
// ---------------------------------------------------------------------------
__global__ __launch_bounds__(256, 2) void k_xz(
    const float* __restrict__ x, const float* __restrict__ W,
    const float* __restrict__ bias, float* __restrict__ xz,
    float* __restrict__ mask)
{
  __shared__ float xl[128 * 64];   // 32 KB, XOR-swizzled rows
  __shared__ float wl[64 * 128];   // 32 KB, plain
  const int tid = threadIdx.x;
  const int m0  = blockIdx.x * 128;
  const int cg  = tid & 15;
  const int rg  = tid >> 4;

  float4 xpre[8], wpre[8];
  int rowbits = 0;

  auto load_chunk = [&](int ch) {
#pragma unroll
    for (int k = 0; k < 8; ++k) {
      const int u = tid + k * 256, r = u >> 4, q = u & 15;
      xpre[k] = *(const float4*)(x + (size_t)(m0 + r) * 128 + ch * 64 + q * 4);
    }
#pragma unroll
    for (int k = 0; k < 8; ++k) {
      const int u = tid + k * 256, f = u >> 5, q = u & 31;
      wpre[k] = *(const float4*)(W + (size_t)(ch * 64 + f) * 128 + q * 4);
    }
  };
  auto mask_chunk = [&]() {
#pragma unroll
    for (int k = 0; k < 8; ++k) {
      const float4 v = xpre[k];
      int nb = ((v.x != 0.f) || (v.y != 0.f) || (v.z != 0.f) || (v.w != 0.f)) ? 1 : 0;
      nb |= __shfl_xor(nb, 1); nb |= __shfl_xor(nb, 2);
      nb |= __shfl_xor(nb, 4); nb |= __shfl_xor(nb, 8);
      rowbits |= nb << k;
    }
  };
  auto write_chunk = [&]() {
#pragma unroll
    for (int k = 0; k < 8; ++k) {
      const int u = tid + k * 256, r = u >> 4, q = u & 15;
      *(float4*)(xl + r * 64 + ((q * 4) ^ (((r >> 3) & 3) << 2))) = xpre[k];
    }
#pragma unroll
    for (int k = 0; k < 8; ++k) {
      const int u = tid + k * 256, f = u >> 5, q = u & 31;
      *(float4*)(wl + f * 128 + q * 4) = wpre[k];
    }
  };

  float acc[8][8];
#pragma unroll
  for (int r = 0; r < 8; ++r)
#pragma unroll
    for (int u = 0; u < 8; ++u) acc[r][u] = 0.f;

  auto compute = [&]() {
#pragma unroll 2
    for (int fq = 0; fq < 16; ++fq) {
      float4 xv[8];
#pragma unroll
      for (int r = 0; r < 8; ++r)
        xv[r] = *(const float4*)(xl + (rg * 8 + r) * 64 + ((fq * 4) ^ ((rg & 3) << 2)));
#pragma unroll
      for (int ff = 0; ff < 4; ++ff) {
        const float* wr = wl + (fq * 4 + ff) * 128 + cg * 4;
        const float4 wa = *(const float4*)(wr);
        const float4 wb = *(const float4*)(wr + 64);
#pragma unroll
        for (int r = 0; r < 8; ++r) {
          const float xs = (ff == 0) ? xv[r].x : (ff == 1) ? xv[r].y
                         : (ff == 2) ? xv[r].z : xv[r].w;
          acc[r][0] += xs * wa.x;  acc[r][1] += xs * wa.y;
          acc[r][2] += xs * wa.z;  acc[r][3] += xs * wa.w;
          acc[r][4] += xs * wb.x;  acc[r][5] += xs * wb.y;
          acc[r][6] += xs * wb.z;  acc[r][7] += xs * wb.w;
        }
      }
    }
  };

  load_chunk(0);
  mask_chunk();
  write_chunk();
  __syncthreads();
  load_chunk(1);
  compute();
  __syncthreads();
  mask_chunk();
  write_chunk();
  __syncthreads();
  compute();

  float bb[8];
#pragma unroll
  for (int u = 0; u < 4; ++u) {
    bb[u]     = bias[cg * 4 + u];
    bb[4 + u] = bias[64 + cg * 4 + u];
  }
#pragma unroll
  for (int r = 0; r < 8; ++r) {
    float* op = xz + (size_t)(m0 + rg * 8 + r) * 128;
    float4 o0 = { acc[r][0] + bb[0], acc[r][1] + bb[1], acc[r][2] + bb[2], acc[r][3] + bb[3] };
    float4 o1 = { acc[r][4] + bb[4], acc[r][5] + bb[5], acc[r][6] + bb[6], acc[r][7] + bb[7] };
    *(float4*)(op + cg * 4)      = o0;
    *(float4*)(op + 64 + cg * 4) = o1;
  }
  if ((tid & 15) == 0) {
#pragma unroll
    for (int k = 0; k < 8; ++k)
      mask[m0 + k * 16 + rg] = (rowbits >> k) & 1 ? 1.f : 0.f;
  }
}

// ---------------------------------------------------------------------------
// Kernel 2: LSTM scan + FC + softmax.  256 blocks x 64 threads (1 wave),
// 2 batch rows/wave (lanes 0-31 row A, 32-63 row B; round-7 verified math:
// f32x2 matvec, LDS hs broadcast, wave_barrier only).
// NEW: gate values staged by global_load_lds DMA (4B/lane), double-buffered
// CH=8-step chunks.  DMA rides vmcnt ONLY -- one manual counted
// s_waitcnt vmcnt(32) + sched_barrier(0) per chunk (never 0 in steady
// state; next chunk's 32 loads stay in flight).  Per-step gate reads are
// stride-1 ds_read_b32 (2-way aliasing = free), consumed at the END of the
// step (z = sum h*W + xg) so ds latency hides under the 64-FMA chain.
// This decouples VMEM latency from the serial path (rounds 2-8 floor of
// 650-770 cyc/step) without round 14's lgkm write/read coupling.
// ---------------------------------------------------------------------------
__device__ __forceinline__ float sigmf(float xx) {
  return __builtin_amdgcn_rcpf(1.f + __expf(-xx));
}
__device__ __forceinline__ float tanhf_(float xx) {
  return __builtin_amdgcn_rcpf(1.f + __expf(-2.f * xx)) * 2.f - 1.f;
}

__global__ __launch_bounds__(64, 1) void k_lstm(
    const float* __restrict__ xz, const float* __restrict__ mask,
    const float* __restrict__ Wh, const float* __restrict__ Wfc,
    const float* __restrict__ bfc, float* __restrict__ out)
{
  __shared__ float xch[2][CH][4][64];   // 16 KB DMA-staged gates [slot][s][g][lane]
  __shared__ float mld[2 * T_];         // 4 KB mask (2 rows)
  __shared__ __align__(16) float hs[2][32];

  const int lane = threadIdx.x;
  const int half = lane >> 5;
  const int j    = lane & 31;
  const int b    = blockIdx.x * 2 + half;

  // mask preload: 2 consecutive rows = 1024 contiguous floats
  {
    const float* mrow = mask + (size_t)(blockIdx.x * 2) * T_;
    float mv[16];
#pragma unroll
    for (int c = 0; c < 16; ++c) mv[c] = mrow[c * 64 + lane];
#pragma unroll
    for (int c = 0; c < 16; ++c) mld[c * 64 + lane] = mv[c];
  }

  // Wh packed in f-pairs: Whr[q][g] = (Wh[2q][g*32+j], Wh[2q+1][g*32+j])
  f32x2 Whr[16][4];
#pragma unroll
  for (int q = 0; q < 16; ++q)
#pragma unroll
    for (int g = 0; g < 4; ++g) {
      Whr[q][g][0] = Wh[(2 * q)     * 128 + g * 32 + j];
      Whr[q][g][1] = Wh[(2 * q + 1) * 128 + g * 32 + j];
    }

  f32x2 hr2[16];
#pragma unroll
  for (int q = 0; q < 16; ++q) { hr2[q][0] = 0.f; hr2[q][1] = 0.f; }
  float cj = 0.f, hj = 0.f;

  // per-lane global gate source: row b, col g*32+j at step t
  const float* xp = xz + (size_t)b * (T_ * 128) + j;

  auto issue_chunk = [&](int k, int slot) {
#pragma unroll
    for (int s = 0; s < CH; ++s) {
      const float* st = xp + (size_t)(k * CH + s) * 128;
#pragma unroll
      for (int g = 0; g < 4; ++g)
        __builtin_amdgcn_global_load_lds(AS1(st + g * 32),
                                         AS3(&xch[slot][s][g][0]), 4, 0, 0);
    }
  };

  issue_chunk(0, 0);                     // prologue: chunk 0 in flight

  for (int k = 0; k < NCH; ++k) {
    const int slot = k & 1;
    if (k + 1 < NCH) {
      issue_chunk(k + 1, slot ^ 1);      // keep 32 loads in flight across chunk
      asm volatile("s_waitcnt vmcnt(32)" ::: "memory");   // chunk k complete
    } else {
      asm volatile("s_waitcnt vmcnt(0)" ::: "memory");
    }
    __builtin_amdgcn_sched_barrier(0);

#pragma unroll
    for (int s = 0; s < CH; ++s) {
      // gate reads issued first; consumed after the FMA chain (latency hidden)
      const float xg0 = xch[slot][s][0][lane];
      const float xg1 = xch[slot][s][1][lane];
      const float xg2 = xch[slot][s][2][lane];
      const float xg3 = xch[slot][s][3][lane];
      const float m   = mld[half * T_ + k * CH + s];

      f32x2 a0 = {0.f, 0.f}, a1 = {0.f, 0.f}, a2 = {0.f, 0.f}, a3 = {0.f, 0.f};
#pragma unroll
      for (int q = 0; q < 16; ++q) {
        a0 += hr2[q] * Whr[q][0];
        a1 += hr2[q] * Whr[q][1];
        a2 += hr2[q] * Whr[q][2];
        a3 += hr2[q] * Whr[q][3];
      }
      const float zi = xg0 + a0[0] + a0[1];
      const float zf = xg1 + a1[0] + a1[1];
      const float zg = xg2 + a2[0] + a2[1];
      const float zo = xg3 + a3[0] + a3[1];

      const float ig = sigmf(zi);
      const float fg = sigmf(zf);
      const float gg = tanhf_(zg);
      const float og = sigmf(zo);
      const float cn = fg * cj + ig * gg;
      const float hn = og * tanhf_(cn);
      cj += m * (cn - cj);               // masked: keep previous state if m==0
      hj += m * (hn - hj);

      hs[half][j] = hj;
      __builtin_amdgcn_wave_barrier();   // sched fence only (single wave)
#pragma unroll
      for (int q = 0; q < 8; ++q) {
        const float4 v = *(const float4*)(&hs[half][q * 4]);
        hr2[2 * q][0]     = v.x; hr2[2 * q][1]     = v.y;
        hr2[2 * q + 1][0] = v.z; hr2[2 * q + 1][1] = v.w;
      }
      __builtin_amdgcn_wave_barrier();   // keep next write after these reads
    }
  }

  // FC + softmax (lane j==0 of each half writes its row)
  float hrs[32];
#pragma unroll
  for (int q = 0; q < 16; ++q) { hrs[2 * q] = hr2[q][0]; hrs[2 * q + 1] = hr2[q][1]; }
  float logits[C_];
#pragma unroll
  for (int c = 0; c < C_; ++c) {
    float aa = bfc[c];
#pragma unroll
    for (int f = 0; f < 32; ++f) aa += hrs[f] * Wfc[f * C_ + c];
    logits[c] = aa;
  }
  if (j == 0) {
    float mx = logits[0];
#pragma unroll
    for (int c = 1; c < C_; ++c) mx = fmaxf(mx, logits[c]);
    float e[C_], sden = 0.f;
#pragma unroll
    for (int c = 0; c < C_; ++c) { e[c] = __expf(logits[c] - mx); sden += e[c]; }
    const float rs = 1.f / sden;
#pragma unroll
    for (int c = 0; c < C_; ++c) out[(size_t)b * C_ + c] = e[c] * rs;
  }
}

// ---------------------------------------------------------------------------
extern "C" void kernel_launch(void* const* d_in, const int* in_sizes, int n_in,
                              void* d_out, int out_size, void* d_ws, size_t ws_size,
                              hipStream_t stream) {
  const float* x   = (const float*)d_in[0];
  const float* Wx  = (const float*)d_in[1];
  const float* Wh  = (const float*)d_in[2];
  const float* bv  = (const float*)d_in[3];
  const float* Wfc = (const float*)d_in[4];
  const float* bfc = (const float*)d_in[5];
  float* out = (float*)d_out;

  float* xz   = (float*)d_ws;                                       // [B][T][128] = 128 MB
  float* mask = (float*)((char*)d_ws + (size_t)B_ * T_ * 128 * 4);  // [B][T] = 1 MB

  k_xz<<<(B_ * T_) / 128, 256, 0, stream>>>(x, Wx, bv, xz, mask);
  k_lstm<<<B_ / 2, 64, 0, stream>>>(xz, mask, Wh, Wfc, bfc, out);
}